// Round 18
// baseline (280.815 us; speedup 1.0000x reference)
//
#include <hip/hip_runtime.h>
#include <hip/hip_bf16.h>
#include <cstdint>

typedef unsigned short u16;
typedef __bf16 __attribute__((ext_vector_type(8))) bf16x8;
typedef float __attribute__((ext_vector_type(4))) f32x4;
typedef float __attribute__((ext_vector_type(16))) f32x16;

#define B_ 8
#define S_ 2048
#define E_ 512
#define H_ 8
#define D_ 64
#define F_ 2048
#define MTOT (B_ * S_)
// 0.125 (1/sqrt(D)) * log2(e): folded into Q so softmax uses exp2 directly.
#define QSCALE 0.18033688011112042f
// Fixed softmax shift (log2 domain); shift-invariant softmax makes it exact.
#define MFIX 12.0f

static __device__ __forceinline__ float bf2f(u16 u) {
    union { uint32_t i; float f; } x;
    x.i = ((uint32_t)u) << 16;
    return x.f;
}
static __device__ __forceinline__ u16 f2bf(float f) {
    __hip_bfloat16 h = __float2bfloat16(f);
    return *reinterpret_cast<u16*>(&h);
}
// single v_exp_f32 (2^x); avoids the libm exp2f slow path (no -ffast-math).
static __device__ __forceinline__ float fast_exp2(float x) {
    float r;
    asm("v_exp_f32 %0, %1" : "=v"(r) : "v"(x));
    return r;
}
static __device__ __forceinline__ float fast_exp2_neg(float x) {  // 2^(-x)
    float r;
    asm("v_exp_f32 %0, -%1" : "=v"(r) : "v"(x));
    return r;
}
static __device__ __forceinline__ float fast_rcp(float x) {
    float r;
    asm("v_rcp_f32 %0, %1" : "=v"(r) : "v"(x));
    return r;
}
// packed f32x2 -> bf16x2 (RNE), single instruction; low = first arg.
static __device__ __forceinline__ uint32_t cvt_pk_bf16(float a, float b) {
    uint32_t r;
    asm("v_cvt_pk_bf16_f32 %0, %1, %2" : "=v"(r) : "v"(a), "v"(b));
    return r;
}
// fast GELU (tanh form) in exp2 domain; |err| vs exact ~1e-3 << 0.11 thresh.
static __device__ __forceinline__ float fast_gelu(float v) {
    float x2 = v * v;
    float w = v * fmaf(0.10294818f, x2, 2.3022066f);
    float e = fast_exp2_neg(w);
    return v * fast_rcp(1.0f + e);
}

// -------------------------------------------------------------- fused prologue
__global__ __launch_bounds__(256) void prep(const float* __restrict__ x,
                                            u16* __restrict__ xb,
                                            const float* __restrict__ WQ,
                                            const float* __restrict__ WK,
                                            const float* __restrict__ WV,
                                            const float* __restrict__ WY,
                                            const float* __restrict__ W1,
                                            const float* __restrict__ W2,
                                            u16* __restrict__ WQKVT,
                                            u16* __restrict__ WYT,
                                            u16* __restrict__ W1T,
                                            u16* __restrict__ W2T,
                                            const float* __restrict__ bQ,
                                            const float* __restrict__ bK,
                                            const float* __restrict__ bV,
                                            float* __restrict__ bqkv) {
    const int bid = blockIdx.x;
    const int tid = threadIdx.x;
    if (bid < 4096) {
        int i = bid * 256 + tid;
        const float4* p = reinterpret_cast<const float4*>(x) + (size_t)i * 2;
        float4 a = p[0], b = p[1];
        uint4 o;
        o.x = cvt_pk_bf16(a.x, a.y);
        o.y = cvt_pk_bf16(a.z, a.w);
        o.z = cvt_pk_bf16(b.x, b.y);
        o.w = cvt_pk_bf16(b.z, b.w);
        *reinterpret_cast<uint4*>(xb + (size_t)i * 8) = o;
        return;
    }
    int r = bid - 4096;
    if (r >= 3072) {
        int i = (r - 3072) * 256 + tid;
        if (i < 1536) bqkv[i] = i < 512 ? bQ[i] : (i < 1024 ? bK[i - 512] : bV[i - 1024]);
        return;
    }
    __shared__ float tile[32][33];
    const float* src;
    u16* dst;
    int K, N, bx, by;
    if (r < 1024) {
        int w = r >> 8, idx = r & 255;
        bx = idx & 15; by = idx >> 4; K = 512; N = 512;
        src = w == 0 ? WQ : (w == 1 ? WK : (w == 2 ? WV : WY));
        dst = (w == 3) ? WYT : (WQKVT + (size_t)w * 512 * 512);
    } else if (r < 2048) {
        int idx = r - 1024;
        bx = idx & 63; by = idx >> 6; K = 512; N = 2048;
        src = W1; dst = W1T;
    } else {
        int idx = r - 2048;
        bx = idx & 15; by = idx >> 4; K = 2048; N = 512;
        src = W2; dst = W2T;
    }
    const int tx = tid & 31, ty = tid >> 5;
    int n0 = bx * 32, k0 = by * 32;
    for (int i = ty; i < 32; i += 8)
        tile[i][tx] = src[(size_t)(k0 + i) * N + n0 + tx];
    __syncthreads();
    for (int i = ty; i < 32; i += 8)
        dst[(size_t)(n0 + i) * K + k0 + tx] = f2bf(tile[tx][i]);
}

// ---------------------------------------------------------------- GEMM
// 128x128 tile, BK=64, 8 waves (wave tile 64x32). Unchanged from R15.
template <int ACT, int SPLIT>
__global__ __launch_bounds__(512) void gemm_bt(const u16* __restrict__ A,
                                               const u16* __restrict__ BT,
                                               const float* __restrict__ bias,
                                               void* __restrict__ Cv,
                                               u16* __restrict__ Vtg,
                                               int Mdim, int Ndim, int Kdim) {
    __shared__ u16 As[128 * 64];
    __shared__ u16 Bs[128 * 64];
    const int tid = threadIdx.x;
    const int wave = tid >> 6, lane = tid & 63;
    const int lr = lane & 15, lg = lane >> 4;

    const int gx = gridDim.x;
    int lin = blockIdx.y * gx + blockIdx.x;
    const int nwg = gx * gridDim.y;
    if ((nwg & 7) == 0) {
        int cpx = nwg >> 3;
        lin = (lin & 7) * cpx + (lin >> 3);
    }
    const int m0 = (lin / gx) * 128, n0 = (lin % gx) * 128;
    const int wrow = (wave >> 2) * 64, wcol = (wave & 3) * 32;

    f32x4 acc[4][2];
#pragma unroll
    for (int i = 0; i < 4; i++)
#pragma unroll
        for (int j = 0; j < 2; j++) acc[i][j] = (f32x4){0.f, 0.f, 0.f, 0.f};

    const int stagerow = tid >> 3;
    const int stagechunk = (tid & 7) * 8;

    for (int k0 = 0; k0 < Kdim; k0 += 64) {
        __syncthreads();
#pragma unroll
        for (int it = 0; it < 2; ++it) {
            int row = stagerow + it * 64;
            const u16* ga = A + (size_t)(m0 + row) * Kdim + k0 + stagechunk;
            const u16* gb = BT + (size_t)(n0 + row) * Kdim + k0 + stagechunk;
            __builtin_amdgcn_global_load_lds(
                (const __attribute__((address_space(1))) void*)ga,
                (__attribute__((address_space(3))) void*)(As + row * 64 + stagechunk),
                16, 0, 0);
            __builtin_amdgcn_global_load_lds(
                (const __attribute__((address_space(1))) void*)gb,
                (__attribute__((address_space(3))) void*)(Bs + row * 64 + stagechunk),
                16, 0, 0);
        }
        __syncthreads();
#pragma unroll
        for (int kk = 0; kk < 64; kk += 32) {
            bf16x8 af[4], bfr[2];
#pragma unroll
            for (int i = 0; i < 4; i++)
                af[i] = *reinterpret_cast<const bf16x8*>(As + (wrow + i * 16 + lr) * 64 + kk + lg * 8);
#pragma unroll
            for (int j = 0; j < 2; j++)
                bfr[j] = *reinterpret_cast<const bf16x8*>(Bs + (wcol + j * 16 + lr) * 64 + kk + lg * 8);
#pragma unroll
            for (int i = 0; i < 4; i++)
#pragma unroll
                for (int j = 0; j < 2; j++)
                    acc[i][j] = __builtin_amdgcn_mfma_f32_16x16x32_bf16(af[i], bfr[j], acc[i][j], 0, 0, 0);
        }
    }

#pragma unroll
    for (int j = 0; j < 2; j++) {
        int col = n0 + wcol + j * 16 + lr;
        float bv = bias[col];
        int seg = col >> 9, c2 = col & 511;
#pragma unroll
        for (int i = 0; i < 4; i++) {
            int rowb = m0 + wrow + i * 16 + lg * 4;
            float vv[4];
#pragma unroll
            for (int r = 0; r < 4; r++) {
                float v = acc[i][j][r] + bv;
                if (ACT == 1) v = fast_gelu(v);
                if (SPLIT) { if (seg == 0) v *= QSCALE; }
                vv[r] = v;
            }
            uint32_t p01 = cvt_pk_bf16(vv[0], vv[1]);
            uint32_t p23 = cvt_pk_bf16(vv[2], vv[3]);
            if (SPLIT) {
                if (seg == 2) {
                    int bb = rowb >> 11, s = rowb & 2047;
                    *reinterpret_cast<uint2*>(Vtg + ((size_t)bb * E_ + c2) * S_ + s) =
                        (uint2){p01, p23};
                } else {
                    u16* dst = (u16*)Cv + (size_t)seg * ((size_t)MTOT * 512) + (size_t)rowb * 512 + c2;
                    dst[0] = (u16)p01; dst[512] = (u16)(p01 >> 16);
                    dst[1024] = (u16)p23; dst[1536] = (u16)(p23 >> 16);
                }
            } else {
                u16* dst = (u16*)Cv + (size_t)rowb * Ndim + col;
                dst[0] = (u16)p01; dst[Ndim] = (u16)(p01 >> 16);
                dst[2 * (size_t)Ndim] = (u16)p23; dst[3 * (size_t)Ndim] = (u16)(p23 >> 16);
            }
        }
    }
}

// ---------------------------------------------------------------- attention
// 32x32-MFMA in-register-P (T12, R17-verified) + QBLK=64/wave: each wave
// owns TWO 32-q groups and SHARES the K/V LDS fragments across both
// (per-wave ds_reads unchanged at 16 b128/tile while wave count halves ->
// per-CU LDS traffic and conflict cycles halve; kernel was LDS-bound).
// 4 waves x 64 q-rows = 256 q-rows/block, grid 512 (2 blocks/CU, 8 waves).
// VGPR ~190 peak (o 64 + sc 64 + qf 32 + pa 32) -> launch_bounds(256,2).
// Shell otherwise identical: XCD-pinned heads, fixed-max softmax,
// permlane P-exchange, K/V single-buffered barrier-covered async staging.
__global__ __launch_bounds__(256, 2) void attn_fwd(const u16* __restrict__ Q,
                                                   const u16* __restrict__ K,
                                                   const u16* __restrict__ Vt,
                                                   u16* __restrict__ Y) {
    __shared__ u16 Ks[64 * 64];
    __shared__ u16 Vs[64 * 64];       // V^T tile: row=d, col=kv
    const int tid = threadIdx.x;
    const int wave = tid >> 6, lane = tid & 63;
    const int l31 = lane & 31, h = lane >> 5;
    const int lin = blockIdx.x;
    const int idx = lin >> 3;
    const int bh = (lin & 7) + 8 * (idx >> 3);  // b*H + h, XCD-pinned
    const int s0 = (idx & 7) * 256;
    const int b = bh >> 3, hd = bh & 7;
    const size_t headoff = ((size_t)b * S_) * E_ + (size_t)hd * D_;
    const size_t vtoff = (size_t)bh * D_ * S_;
    const int qb = s0 + wave * 64;
    const int sw31 = l31 & 7;  // swizzle key for rows l31 and 32+l31

    // Q fragments (B-operand), two q-groups:
    // qf[qg][db] = Q[qb + qg*32 + l31][db*16 + h*8 .. +7]
    bf16x8 qf[2][4];
#pragma unroll
    for (int qg = 0; qg < 2; qg++) {
        const u16* qrow = Q + headoff + (size_t)(qb + qg * 32 + l31) * E_ + h * 8;
#pragma unroll
        for (int db = 0; db < 4; db++)
            qf[qg][db] = *reinterpret_cast<const bf16x8*>(qrow + db * 16);
    }
    f32x16 o[2][2];  // [qg][d-half]
#pragma unroll
    for (int qg = 0; qg < 2; qg++)
#pragma unroll
        for (int dh = 0; dh < 2; dh++)
#pragma unroll
            for (int e = 0; e < 16; e++) o[qg][dh][e] = 0.f;
    float lrow[2] = {0.f, 0.f};

    const int r8 = lane >> 3, c8 = lane & 7;
    const int srcch = c8 ^ r8;

    auto STAGE_K = [&](int t) {
#pragma unroll
        for (int it = 0; it < 2; ++it) {
            int row = wave * 8 + it * 32 + r8;  // row&7 == r8
            const u16* gk = K + headoff + (size_t)(t * 64 + row) * E_ + srcch * 8;
            __builtin_amdgcn_global_load_lds(
                (const __attribute__((address_space(1))) void*)gk,
                (__attribute__((address_space(3))) void*)(Ks + row * 64 + c8 * 8), 16, 0, 0);
        }
    };
    auto STAGE_V = [&](int t) {
#pragma unroll
        for (int it = 0; it < 2; ++it) {
            int row = wave * 8 + it * 32 + r8;
            const u16* gv = Vt + vtoff + (size_t)row * S_ + t * 64 + srcch * 8;
            __builtin_amdgcn_global_load_lds(
                (const __attribute__((address_space(1))) void*)gv,
                (__attribute__((address_space(3))) void*)(Vs + row * 64 + c8 * 8), 16, 0, 0);
        }
    };

    STAGE_K(0);
    STAGE_V(0);
    __syncthreads();

    for (int t = 0; t < S_ / 64; ++t) {
        // ---- QK^T: sc[qg][kh] = K(rows kh*32..+31) . Q(qg)^T + (-MFIX)
        // K fragments (a0,a1) shared across both q-groups.
        f32x16 sc[2][2];
#pragma unroll
        for (int qg = 0; qg < 2; qg++)
#pragma unroll
            for (int kh = 0; kh < 2; kh++)
#pragma unroll
                for (int e = 0; e < 16; e++) sc[qg][kh][e] = -MFIX;
        __builtin_amdgcn_s_setprio(1);
#pragma unroll
        for (int db = 0; db < 4; db++) {
            int cc = ((db * 2 + h) ^ sw31) * 8;
            bf16x8 a0 = *reinterpret_cast<const bf16x8*>(Ks + l31 * 64 + cc);
            bf16x8 a1 = *reinterpret_cast<const bf16x8*>(Ks + (32 + l31) * 64 + cc);
#pragma unroll
            for (int qg = 0; qg < 2; qg++) {
                sc[qg][0] = __builtin_amdgcn_mfma_f32_32x32x16_bf16(a0, qf[qg][db], sc[qg][0], 0, 0, 0);
                sc[qg][1] = __builtin_amdgcn_mfma_f32_32x32x16_bf16(a1, qf[qg][db], sc[qg][1], 0, 0, 0);
            }
        }
        __builtin_amdgcn_s_setprio(0);
        __syncthreads();                       // (a): all waves done reading Ks
        if (t + 1 < S_ / 64) STAGE_K(t + 1);   // async overwrite, drains at (b)

        // ---- softmax (fixed shift) + pack + permlane -> PV A-fragments
        bf16x8 paa[2][4];
#pragma unroll
        for (int qg = 0; qg < 2; qg++) {
            float rs = 0.f;
#pragma unroll
            for (int kh = 0; kh < 2; kh++) {
#pragma unroll
                for (int f = 0; f < 2; f++) {
                    float p[8];
#pragma unroll
                    for (int e = 0; e < 8; e++)
                        p[e] = fast_exp2(sc[qg][kh][f * 8 + e]);
                    rs += ((p[0] + p[1]) + (p[2] + p[3])) + ((p[4] + p[5]) + (p[6] + p[7]));
                    uint32_t x0 = cvt_pk_bf16(p[0], p[1]);
                    uint32_t x1 = cvt_pk_bf16(p[2], p[3]);
                    uint32_t y0 = cvt_pk_bf16(p[4], p[5]);
                    uint32_t y1 = cvt_pk_bf16(p[6], p[7]);
                    // v_permlane32_swap_b32 A,B: A'={A.lo,B.lo}; B'={A.hi,B.hi}
                    asm("v_permlane32_swap_b32 %0, %1" : "+v"(x0), "+v"(y0));
                    asm("v_permlane32_swap_b32 %0, %1" : "+v"(x1), "+v"(y1));
                    uint4 av = {x0, x1, y0, y1};  // A[q][k=slot*16+h*8+e]
                    paa[qg][kh * 2 + f] = *reinterpret_cast<const bf16x8*>(&av);
                }
            }
            rs += __shfl_xor(rs, 32);
            lrow[qg] += rs;
        }

        // ---- PV: O[qg][d] += P . V ; V fragments shared across q-groups
        __builtin_amdgcn_s_setprio(1);
#pragma unroll
        for (int s = 0; s < 4; s++) {
            int cc = ((s * 2 + h) ^ sw31) * 8;
            bf16x8 bv0 = *reinterpret_cast<const bf16x8*>(Vs + l31 * 64 + cc);
            bf16x8 bv1 = *reinterpret_cast<const bf16x8*>(Vs + (32 + l31) * 64 + cc);
#pragma unroll
            for (int qg = 0; qg < 2; qg++) {
                o[qg][0] = __builtin_amdgcn_mfma_f32_32x32x16_bf16(paa[qg][s], bv0, o[qg][0], 0, 0, 0);
                o[qg][1] = __builtin_amdgcn_mfma_f32_32x32x16_bf16(paa[qg][s], bv1, o[qg][1], 0, 0, 0);
            }
        }
        __builtin_amdgcn_s_setprio(0);
        __syncthreads();                       // (b): all waves done reading Vs
        if (t + 1 < S_ / 64) STAGE_V(t + 1);   // async overwrite, drains at next (a)
    }

    // ---- epilogue: C-layout row q=(r&3)+8*(r>>2)+4h, col d = dh*32+l31
#pragma unroll
    for (int qg = 0; qg < 2; qg++) {
#pragma unroll
        for (int r = 0; r < 16; r++) {
            int q = (r & 3) + 8 * (r >> 2) + 4 * h;
            float rl = fast_rcp(__shfl(lrow[qg], q));
            u16* dst = Y + headoff + (size_t)(qb + qg * 32 + q) * E_ + l31;
            dst[0] = f2bf(o[qg][0][r] * rl);
            dst[32] = f2bf(o[qg][1][r] * rl);
        }
    }
}

// ------------------------------------------------- residual+LN (bf16 inputs)
template <int F32OUT>
__global__ __launch_bounds__(256) void resid_ln(const u16* __restrict__ X,
                                                const u16* __restrict__ Yres,
                                                const float* __restrict__ W,
                                                const float* __restrict__ Bb,
                                                void* __restrict__ H) {
    const int tid = threadIdx.x;
    const int wave = tid >> 6, lane = tid & 63;
    const size_t row = (size_t)blockIdx.x * 4 + wave;
    uint4 xa = *reinterpret_cast<const uint4*>(X + row * E_ + lane * 8);
    uint4 ya = *reinterpret_cast<const uint4*>(Yres + row * E_ + lane * 8);
    const u16* xu = reinterpret_cast<const u16*>(&xa);
    const u16* yu = reinterpret_cast<const u16*>(&ya);
    float v[8];
    float s = 0.f, sq = 0.f;
#pragma unroll
    for (int e = 0; e < 8; e++) {
        v[e] = bf2f(xu[e]) + bf2f(yu[e]);
        s += v[e];
        sq += v[e] * v[e];
    }
#pragma unroll
    for (int msk = 1; msk < 64; msk <<= 1) {
        s += __shfl_xor(s, msk);
        sq += __shfl_xor(sq, msk);
    }
    float mean = s * (1.f / E_);
    float var = fmaxf(sq * (1.f / E_) - mean * mean, 0.f);
    float rstd = 1.f / (sqrtf(var) + 1e-5f);
    const float4* wr = reinterpret_cast<const float4*>(W + lane * 8);
    const float4* br = reinterpret_cast<const float4*>(Bb + lane * 8);
    float4 w0 = wr[0], w1 = wr[1], b0 = br[0], b1 = br[1];
    float wv[8] = {w0.x, w0.y, w0.z, w0.w, w1.x, w1.y, w1.z, w1.w};
    float bv[8] = {b0.x, b0.y, b0.z, b0.w, b1.x, b1.y, b1.z, b1.w};
    float out[8];
#pragma unroll
    for (int e = 0; e < 8; e++) out[e] = (v[e] - mean) * rstd * wv[e] + bv[e];
    if (F32OUT) {
        float4* hw = reinterpret_cast<float4*>((float*)H + row * E_ + lane * 8);
        hw[0] = (float4){out[0], out[1], out[2], out[3]};
        hw[1] = (float4){out[4], out[5], out[6], out[7]};
    } else {
        uint4 ob;
        ob.x = cvt_pk_bf16(out[0], out[1]);
        ob.y = cvt_pk_bf16(out[2], out[3]);
        ob.z = cvt_pk_bf16(out[4], out[5]);
        ob.w = cvt_pk_bf16(out[6], out[7]);
        *reinterpret_cast<uint4*>((u16*)H + row * E_ + lane * 8) = ob;
    }
}

// ---------------------------------------------------------------- launch
extern "C" void kernel_launch(void* const* d_in, const int* in_sizes, int n_in,
                              void* d_out, int out_size, void* d_ws, size_t ws_size,
                              hipStream_t stream) {
    const float* x = (const float*)d_in[0];
    const float* WQ = (const float*)d_in[1];
    const float* bQ = (const float*)d_in[2];
    const float* WK = (const float*)d_in[3];
    const float* bK = (const float*)d_in[4];
    const float* WV = (const float*)d_in[5];
    const float* bV = (const float*)d_in[6];
    const float* WY = (const float*)d_in[7];
    const float* bY = (const float*)d_in[8];
    const float* ln1w = (const float*)d_in[9];
    const float* ln1b = (const float*)d_in[10];
    const float* W1 = (const float*)d_in[11];
    const float* b1 = (const float*)d_in[12];
    const float* W2 = (const float*)d_in[13];
    const float* b2 = (const float*)d_in[14];
    const float* ln2w = (const float*)d_in[15];
    const float* ln2b = (const float*)d_in[16];

    char* ws = (char*)d_ws;
    const size_t MB = 1024 * 1024;
    u16* WQKVT = (u16*)(ws);                              // 1.5 MiB
    u16* WYT = (u16*)(ws + (size_t)1536 * 1024);          // 0.5 MiB
    u16* W1T = (u16*)(ws + 2 * MB);                       // 2 MiB
    u16* W2T = (u16*)(ws + 4 * MB);                       // 2 MiB
    float* bqkv = (float*)(ws + 6 * MB);                  // 6 KiB
    // activation overlays (peak 103 MiB):
    u16* xb   = (u16*)(ws + 7 * MB);    // 7..23   (alive until LN1)
    u16* Qb   = (u16*)(ws + 23 * MB);   // 23..39
    u16* Kb   = (u16*)(ws + 39 * MB);   // 39..55
    u16* Vtg  = (u16*)(ws + 55 * MB);   // 55..71
    u16* Yb   = (u16*)(ws + 71 * MB);   // 71..87
    u16* attnb = Vtg;                   // 55..71 (Vtg dead after attn)
    u16* hb   = Qb;                     // 23..39 (Qb dead after attn)
    u16* hid  = Kb;                     // 39..103 (64 MiB)
    u16* m2b  = xb;                     // 7..23   (xb dead after LN1)

    dim3 blk(256);
    dim3 gblk(512);
    prep<<<dim3(7174), blk, 0, stream>>>(x, xb, WQ, WK, WV, WY, W1, W2,
                                         WQKVT, WYT, W1T, W2T, bQ, bK, bV, bqkv);
    gemm_bt<0, 1><<<dim3(12, 128), gblk, 0, stream>>>(xb, WQKVT, bqkv, Qb, Vtg, MTOT, 1536, 512);
    attn_fwd<<<dim3(512), blk, 0, stream>>>(Qb, Kb, Vtg, Yb);
    gemm_bt<0, 0><<<dim3(4, 128), gblk, 0, stream>>>(Yb, WYT, bY, attnb, nullptr, MTOT, 512, 512);
    resid_ln<0><<<dim3(4096), blk, 0, stream>>>(xb, attnb, ln1w, ln1b, hb);
    gemm_bt<1, 0><<<dim3(16, 128), gblk, 0, stream>>>(hb, W1T, b1, hid, nullptr, MTOT, 2048, 512);
    gemm_bt<0, 0><<<dim3(4, 128), gblk, 0, stream>>>(hid, W2T, b2, m2b, nullptr, MTOT, 512, 2048);
    resid_ln<1><<<dim3(4096), blk, 0, stream>>>(hb, m2b, ln2w, ln2b, (float*)d_out);
}

// Round 19
// 277.578 us; speedup vs baseline: 1.0117x; 1.0117x over previous
//
#include <hip/hip_runtime.h>
#include <hip/hip_bf16.h>
#include <cstdint>

typedef unsigned short u16;
typedef __bf16 __attribute__((ext_vector_type(8))) bf16x8;
typedef float __attribute__((ext_vector_type(4))) f32x4;
typedef float __attribute__((ext_vector_type(16))) f32x16;

#define B_ 8
#define S_ 2048
#define E_ 512
#define H_ 8
#define D_ 64
#define F_ 2048
#define MTOT (B_ * S_)
// 0.125 (1/sqrt(D)) * log2(e): folded into Q so softmax uses exp2 directly.
#define QSCALE 0.18033688011112042f
// Fixed softmax shift (log2 domain); shift-invariant softmax makes it exact.
#define MFIX 12.0f

static __device__ __forceinline__ float bf2f(u16 u) {
    union { uint32_t i; float f; } x;
    x.i = ((uint32_t)u) << 16;
    return x.f;
}
static __device__ __forceinline__ u16 f2bf(float f) {
    __hip_bfloat16 h = __float2bfloat16(f);
    return *reinterpret_cast<u16*>(&h);
}
// single v_exp_f32 (2^x); avoids the libm exp2f slow path (no -ffast-math).
static __device__ __forceinline__ float fast_exp2(float x) {
    float r;
    asm("v_exp_f32 %0, %1" : "=v"(r) : "v"(x));
    return r;
}
static __device__ __forceinline__ float fast_exp2_neg(float x) {  // 2^(-x)
    float r;
    asm("v_exp_f32 %0, -%1" : "=v"(r) : "v"(x));
    return r;
}
static __device__ __forceinline__ float fast_rcp(float x) {
    float r;
    asm("v_rcp_f32 %0, %1" : "=v"(r) : "v"(x));
    return r;
}
// packed f32x2 -> bf16x2 (RNE), single instruction; low = first arg.
static __device__ __forceinline__ uint32_t cvt_pk_bf16(float a, float b) {
    uint32_t r;
    asm("v_cvt_pk_bf16_f32 %0, %1, %2" : "=v"(r) : "v"(a), "v"(b));
    return r;
}
// fast GELU (tanh form) in exp2 domain; |err| vs exact ~1e-3 << 0.11 thresh.
static __device__ __forceinline__ float fast_gelu(float v) {
    float x2 = v * v;
    float w = v * fmaf(0.10294818f, x2, 2.3022066f);
    float e = fast_exp2_neg(w);
    return v * fast_rcp(1.0f + e);
}

// -------------------------------------------------------------- fused prologue
__global__ __launch_bounds__(256) void prep(const float* __restrict__ x,
                                            u16* __restrict__ xb,
                                            const float* __restrict__ WQ,
                                            const float* __restrict__ WK,
                                            const float* __restrict__ WV,
                                            const float* __restrict__ WY,
                                            const float* __restrict__ W1,
                                            const float* __restrict__ W2,
                                            u16* __restrict__ WQKVT,
                                            u16* __restrict__ WYT,
                                            u16* __restrict__ W1T,
                                            u16* __restrict__ W2T,
                                            const float* __restrict__ bQ,
                                            const float* __restrict__ bK,
                                            const float* __restrict__ bV,
                                            float* __restrict__ bqkv) {
    const int bid = blockIdx.x;
    const int tid = threadIdx.x;
    if (bid < 4096) {
        int i = bid * 256 + tid;
        const float4* p = reinterpret_cast<const float4*>(x) + (size_t)i * 2;
        float4 a = p[0], b = p[1];
        uint4 o;
        o.x = cvt_pk_bf16(a.x, a.y);
        o.y = cvt_pk_bf16(a.z, a.w);
        o.z = cvt_pk_bf16(b.x, b.y);
        o.w = cvt_pk_bf16(b.z, b.w);
        *reinterpret_cast<uint4*>(xb + (size_t)i * 8) = o;
        return;
    }
    int r = bid - 4096;
    if (r >= 3072) {
        int i = (r - 3072) * 256 + tid;
        if (i < 1536) bqkv[i] = i < 512 ? bQ[i] : (i < 1024 ? bK[i - 512] : bV[i - 1024]);
        return;
    }
    __shared__ float tile[32][33];
    const float* src;
    u16* dst;
    int K, N, bx, by;
    if (r < 1024) {
        int w = r >> 8, idx = r & 255;
        bx = idx & 15; by = idx >> 4; K = 512; N = 512;
        src = w == 0 ? WQ : (w == 1 ? WK : (w == 2 ? WV : WY));
        dst = (w == 3) ? WYT : (WQKVT + (size_t)w * 512 * 512);
    } else if (r < 2048) {
        int idx = r - 1024;
        bx = idx & 63; by = idx >> 6; K = 512; N = 2048;
        src = W1; dst = W1T;
    } else {
        int idx = r - 2048;
        bx = idx & 15; by = idx >> 4; K = 2048; N = 512;
        src = W2; dst = W2T;
    }
    const int tx = tid & 31, ty = tid >> 5;
    int n0 = bx * 32, k0 = by * 32;
    for (int i = ty; i < 32; i += 8)
        tile[i][tx] = src[(size_t)(k0 + i) * N + n0 + tx];
    __syncthreads();
    for (int i = ty; i < 32; i += 8)
        dst[(size_t)(n0 + i) * K + k0 + tx] = f2bf(tile[tx][i]);
}

// ---------------------------------------------------------------- GEMM
// 128x128 tile, BK=64, 8 waves (wave tile 64x32). Unchanged from R15.
template <int ACT, int SPLIT>
__global__ __launch_bounds__(512) void gemm_bt(const u16* __restrict__ A,
                                               const u16* __restrict__ BT,
                                               const float* __restrict__ bias,
                                               void* __restrict__ Cv,
                                               u16* __restrict__ Vtg,
                                               int Mdim, int Ndim, int Kdim) {
    __shared__ u16 As[128 * 64];
    __shared__ u16 Bs[128 * 64];
    const int tid = threadIdx.x;
    const int wave = tid >> 6, lane = tid & 63;
    const int lr = lane & 15, lg = lane >> 4;

    const int gx = gridDim.x;
    int lin = blockIdx.y * gx + blockIdx.x;
    const int nwg = gx * gridDim.y;
    if ((nwg & 7) == 0) {
        int cpx = nwg >> 3;
        lin = (lin & 7) * cpx + (lin >> 3);
    }
    const int m0 = (lin / gx) * 128, n0 = (lin % gx) * 128;
    const int wrow = (wave >> 2) * 64, wcol = (wave & 3) * 32;

    f32x4 acc[4][2];
#pragma unroll
    for (int i = 0; i < 4; i++)
#pragma unroll
        for (int j = 0; j < 2; j++) acc[i][j] = (f32x4){0.f, 0.f, 0.f, 0.f};

    const int stagerow = tid >> 3;
    const int stagechunk = (tid & 7) * 8;

    for (int k0 = 0; k0 < Kdim; k0 += 64) {
        __syncthreads();
#pragma unroll
        for (int it = 0; it < 2; ++it) {
            int row = stagerow + it * 64;
            const u16* ga = A + (size_t)(m0 + row) * Kdim + k0 + stagechunk;
            const u16* gb = BT + (size_t)(n0 + row) * Kdim + k0 + stagechunk;
            __builtin_amdgcn_global_load_lds(
                (const __attribute__((address_space(1))) void*)ga,
                (__attribute__((address_space(3))) void*)(As + row * 64 + stagechunk),
                16, 0, 0);
            __builtin_amdgcn_global_load_lds(
                (const __attribute__((address_space(1))) void*)gb,
                (__attribute__((address_space(3))) void*)(Bs + row * 64 + stagechunk),
                16, 0, 0);
        }
        __syncthreads();
#pragma unroll
        for (int kk = 0; kk < 64; kk += 32) {
            bf16x8 af[4], bfr[2];
#pragma unroll
            for (int i = 0; i < 4; i++)
                af[i] = *reinterpret_cast<const bf16x8*>(As + (wrow + i * 16 + lr) * 64 + kk + lg * 8);
#pragma unroll
            for (int j = 0; j < 2; j++)
                bfr[j] = *reinterpret_cast<const bf16x8*>(Bs + (wcol + j * 16 + lr) * 64 + kk + lg * 8);
#pragma unroll
            for (int i = 0; i < 4; i++)
#pragma unroll
                for (int j = 0; j < 2; j++)
                    acc[i][j] = __builtin_amdgcn_mfma_f32_16x16x32_bf16(af[i], bfr[j], acc[i][j], 0, 0, 0);
        }
    }

#pragma unroll
    for (int j = 0; j < 2; j++) {
        int col = n0 + wcol + j * 16 + lr;
        float bv = bias[col];
        int seg = col >> 9, c2 = col & 511;
#pragma unroll
        for (int i = 0; i < 4; i++) {
            int rowb = m0 + wrow + i * 16 + lg * 4;
            float vv[4];
#pragma unroll
            for (int r = 0; r < 4; r++) {
                float v = acc[i][j][r] + bv;
                if (ACT == 1) v = fast_gelu(v);
                if (SPLIT) { if (seg == 0) v *= QSCALE; }
                vv[r] = v;
            }
            uint32_t p01 = cvt_pk_bf16(vv[0], vv[1]);
            uint32_t p23 = cvt_pk_bf16(vv[2], vv[3]);
            if (SPLIT) {
                if (seg == 2) {
                    int bb = rowb >> 11, s = rowb & 2047;
                    *reinterpret_cast<uint2*>(Vtg + ((size_t)bb * E_ + c2) * S_ + s) =
                        (uint2){p01, p23};
                } else {
                    u16* dst = (u16*)Cv + (size_t)seg * ((size_t)MTOT * 512) + (size_t)rowb * 512 + c2;
                    dst[0] = (u16)p01; dst[512] = (u16)(p01 >> 16);
                    dst[1024] = (u16)p23; dst[1536] = (u16)(p23 >> 16);
                }
            } else {
                u16* dst = (u16*)Cv + (size_t)rowb * Ndim + col;
                dst[0] = (u16)p01; dst[Ndim] = (u16)(p01 >> 16);
                dst[2 * (size_t)Ndim] = (u16)p23; dst[3 * (size_t)Ndim] = (u16)(p23 >> 16);
            }
        }
    }
}

// ---------------------------------------------------------------- attention
// REVERTED to the R17 configuration (best measured: 76.6 us). 32x32-MFMA
// in-register-P (T12): swapped QK^T leaves P^T in the C layout (q=lane&31,
// k=(r&3)+8*(r>>2)+4*(lane>>5)); cvt_pk + one v_permlane32_swap_b32 per
// word pair (A'={A.lo,B.lo}; B'={A.hi,B.hi}) yields the PV A-fragment
// (k = slot*16 + h*8 + e). NO LDS for P. 8 waves x 32 q-rows = 256
// q-rows/block, grid 512 (2 blocks/CU, 16 waves/CU). R18's QBLK=64/wave
// variant halved LDS traffic but dropped to 8 waves/CU and REGRESSED
// (85.8 us) -- this point balances reuse vs TLP.
__global__ __launch_bounds__(512, 4) void attn_fwd(const u16* __restrict__ Q,
                                                   const u16* __restrict__ K,
                                                   const u16* __restrict__ Vt,
                                                   u16* __restrict__ Y) {
    __shared__ u16 Ks[64 * 64];
    __shared__ u16 Vs[64 * 64];       // V^T tile: row=d, col=kv
    const int tid = threadIdx.x;
    const int wave = tid >> 6, lane = tid & 63;
    const int l31 = lane & 31, h = lane >> 5;
    const int lin = blockIdx.x;
    const int idx = lin >> 3;
    const int bh = (lin & 7) + 8 * (idx >> 3);  // b*H + h, XCD-pinned
    const int s0 = (idx & 7) * 256;
    const int b = bh >> 3, hd = bh & 7;
    const size_t headoff = ((size_t)b * S_) * E_ + (size_t)hd * D_;
    const size_t vtoff = (size_t)bh * D_ * S_;
    const int qb = s0 + wave * 32;
    const int sw31 = l31 & 7;  // swizzle key for rows l31 and 32+l31

    // Q fragments (B-operand): qf[db] = Q[qb + l31][db*16 + h*8 .. +7]
    bf16x8 qf[4];
    {
        const u16* qrow = Q + headoff + (size_t)(qb + l31) * E_ + h * 8;
#pragma unroll
        for (int db = 0; db < 4; db++)
            qf[db] = *reinterpret_cast<const bf16x8*>(qrow + db * 16);
    }
    f32x16 o0 = {0.f, 0.f, 0.f, 0.f, 0.f, 0.f, 0.f, 0.f,
                 0.f, 0.f, 0.f, 0.f, 0.f, 0.f, 0.f, 0.f};
    f32x16 o1 = o0;
    float lrow = 0.f;

    const int r8 = lane >> 3, c8 = lane & 7;
    const int srcch = c8 ^ r8;
    const int strow = wave * 8 + r8;  // staging row; strow&7==r8

    auto STAGE_K = [&](int t) {
        const u16* gk = K + headoff + (size_t)(t * 64 + strow) * E_ + srcch * 8;
        __builtin_amdgcn_global_load_lds(
            (const __attribute__((address_space(1))) void*)gk,
            (__attribute__((address_space(3))) void*)(Ks + strow * 64 + c8 * 8), 16, 0, 0);
    };
    auto STAGE_V = [&](int t) {
        const u16* gv = Vt + vtoff + (size_t)strow * S_ + t * 64 + srcch * 8;
        __builtin_amdgcn_global_load_lds(
            (const __attribute__((address_space(1))) void*)gv,
            (__attribute__((address_space(3))) void*)(Vs + strow * 64 + c8 * 8), 16, 0, 0);
    };

    STAGE_K(0);
    STAGE_V(0);
    __syncthreads();

    for (int t = 0; t < S_ / 64; ++t) {
        // ---- QK^T: sc[kh] = K(rows kh*32..+31) . Q^T  + (-MFIX)
        f32x16 sc0 = {-MFIX, -MFIX, -MFIX, -MFIX, -MFIX, -MFIX, -MFIX, -MFIX,
                      -MFIX, -MFIX, -MFIX, -MFIX, -MFIX, -MFIX, -MFIX, -MFIX};
        f32x16 sc1 = sc0;
        __builtin_amdgcn_s_setprio(1);
#pragma unroll
        for (int db = 0; db < 4; db++) {
            int cc = ((db * 2 + h) ^ sw31) * 8;
            bf16x8 a0 = *reinterpret_cast<const bf16x8*>(Ks + l31 * 64 + cc);
            bf16x8 a1 = *reinterpret_cast<const bf16x8*>(Ks + (32 + l31) * 64 + cc);
            sc0 = __builtin_amdgcn_mfma_f32_32x32x16_bf16(a0, qf[db], sc0, 0, 0, 0);
            sc1 = __builtin_amdgcn_mfma_f32_32x32x16_bf16(a1, qf[db], sc1, 0, 0, 0);
        }
        __builtin_amdgcn_s_setprio(0);
        __syncthreads();                       // (a): all waves done reading Ks
        if (t + 1 < S_ / 64) STAGE_K(t + 1);   // async overwrite, drains at (b)

        // ---- softmax (fixed shift) + pack + permlane -> 4 PV A-fragments
        bf16x8 pa[4];
        float rs = 0.f;
#pragma unroll
        for (int kh = 0; kh < 2; kh++) {
#pragma unroll
            for (int f = 0; f < 2; f++) {
                float p0, p1, p2, p3, p4, p5, p6, p7;
                if (kh == 0) {
                    if (f == 0) {
                        p0 = fast_exp2(sc0[0]); p1 = fast_exp2(sc0[1]);
                        p2 = fast_exp2(sc0[2]); p3 = fast_exp2(sc0[3]);
                        p4 = fast_exp2(sc0[4]); p5 = fast_exp2(sc0[5]);
                        p6 = fast_exp2(sc0[6]); p7 = fast_exp2(sc0[7]);
                    } else {
                        p0 = fast_exp2(sc0[8]);  p1 = fast_exp2(sc0[9]);
                        p2 = fast_exp2(sc0[10]); p3 = fast_exp2(sc0[11]);
                        p4 = fast_exp2(sc0[12]); p5 = fast_exp2(sc0[13]);
                        p6 = fast_exp2(sc0[14]); p7 = fast_exp2(sc0[15]);
                    }
                } else {
                    if (f == 0) {
                        p0 = fast_exp2(sc1[0]); p1 = fast_exp2(sc1[1]);
                        p2 = fast_exp2(sc1[2]); p3 = fast_exp2(sc1[3]);
                        p4 = fast_exp2(sc1[4]); p5 = fast_exp2(sc1[5]);
                        p6 = fast_exp2(sc1[6]); p7 = fast_exp2(sc1[7]);
                    } else {
                        p0 = fast_exp2(sc1[8]);  p1 = fast_exp2(sc1[9]);
                        p2 = fast_exp2(sc1[10]); p3 = fast_exp2(sc1[11]);
                        p4 = fast_exp2(sc1[12]); p5 = fast_exp2(sc1[13]);
                        p6 = fast_exp2(sc1[14]); p7 = fast_exp2(sc1[15]);
                    }
                }
                rs += ((p0 + p1) + (p2 + p3)) + ((p4 + p5) + (p6 + p7));
                uint32_t x0 = cvt_pk_bf16(p0, p1);
                uint32_t x1 = cvt_pk_bf16(p2, p3);
                uint32_t y0 = cvt_pk_bf16(p4, p5);
                uint32_t y1 = cvt_pk_bf16(p6, p7);
                // v_permlane32_swap_b32 A,B: A' = {A.lo, B.lo}; B' = {A.hi, B.hi}
                asm("v_permlane32_swap_b32 %0, %1" : "+v"(x0), "+v"(y0));
                asm("v_permlane32_swap_b32 %0, %1" : "+v"(x1), "+v"(y1));
                uint4 av = {x0, x1, y0, y1};  // A[q][k=slot*16+h*8+e], e=0..7
                pa[kh * 2 + f] = *reinterpret_cast<const bf16x8*>(&av);
            }
        }
        rs += __shfl_xor(rs, 32);
        lrow += rs;

        // ---- PV: O[q][d] += P . V   (4 k-slots x 2 d-halves)
        __builtin_amdgcn_s_setprio(1);
#pragma unroll
        for (int s = 0; s < 4; s++) {
            int cc = ((s * 2 + h) ^ sw31) * 8;
            bf16x8 bv0 = *reinterpret_cast<const bf16x8*>(Vs + l31 * 64 + cc);
            bf16x8 bv1 = *reinterpret_cast<const bf16x8*>(Vs + (32 + l31) * 64 + cc);
            o0 = __builtin_amdgcn_mfma_f32_32x32x16_bf16(pa[s], bv0, o0, 0, 0, 0);
            o1 = __builtin_amdgcn_mfma_f32_32x32x16_bf16(pa[s], bv1, o1, 0, 0, 0);
        }
        __builtin_amdgcn_s_setprio(0);
        __syncthreads();                       // (b): all waves done reading Vs
        if (t + 1 < S_ / 64) STAGE_V(t + 1);   // async overwrite, drains at next (a)
    }

    // ---- epilogue: O C-layout row q=(r&3)+8*(r>>2)+4h, col d = dh*32+l31
#pragma unroll
    for (int r = 0; r < 16; r++) {
        int q = (r & 3) + 8 * (r >> 2) + 4 * h;
        float rl = fast_rcp(__shfl(lrow, q));
        u16* dst = Y + headoff + (size_t)(qb + q) * E_ + l31;
        dst[0] = f2bf(o0[r] * rl);
        dst[32] = f2bf(o1[r] * rl);
    }
}

// ------------------------------------------------- residual+LN (bf16 inputs)
template <int F32OUT>
__global__ __launch_bounds__(256) void resid_ln(const u16* __restrict__ X,
                                                const u16* __restrict__ Yres,
                                                const float* __restrict__ W,
                                                const float* __restrict__ Bb,
                                                void* __restrict__ H) {
    const int tid = threadIdx.x;
    const int wave = tid >> 6, lane = tid & 63;
    const size_t row = (size_t)blockIdx.x * 4 + wave;
    uint4 xa = *reinterpret_cast<const uint4*>(X + row * E_ + lane * 8);
    uint4 ya = *reinterpret_cast<const uint4*>(Yres + row * E_ + lane * 8);
    const u16* xu = reinterpret_cast<const u16*>(&xa);
    const u16* yu = reinterpret_cast<const u16*>(&ya);
    float v[8];
    float s = 0.f, sq = 0.f;
#pragma unroll
    for (int e = 0; e < 8; e++) {
        v[e] = bf2f(xu[e]) + bf2f(yu[e]);
        s += v[e];
        sq += v[e] * v[e];
    }
#pragma unroll
    for (int msk = 1; msk < 64; msk <<= 1) {
        s += __shfl_xor(s, msk);
        sq += __shfl_xor(sq, msk);
    }
    float mean = s * (1.f / E_);
    float var = fmaxf(sq * (1.f / E_) - mean * mean, 0.f);
    float rstd = 1.f / (sqrtf(var) + 1e-5f);
    const float4* wr = reinterpret_cast<const float4*>(W + lane * 8);
    const float4* br = reinterpret_cast<const float4*>(Bb + lane * 8);
    float4 w0 = wr[0], w1 = wr[1], b0 = br[0], b1 = br[1];
    float wv[8] = {w0.x, w0.y, w0.z, w0.w, w1.x, w1.y, w1.z, w1.w};
    float bv[8] = {b0.x, b0.y, b0.z, b0.w, b1.x, b1.y, b1.z, b1.w};
    float out[8];
#pragma unroll
    for (int e = 0; e < 8; e++) out[e] = (v[e] - mean) * rstd * wv[e] + bv[e];
    if (F32OUT) {
        float4* hw = reinterpret_cast<float4*>((float*)H + row * E_ + lane * 8);
        hw[0] = (float4){out[0], out[1], out[2], out[3]};
        hw[1] = (float4){out[4], out[5], out[6], out[7]};
    } else {
        uint4 ob;
        ob.x = cvt_pk_bf16(out[0], out[1]);
        ob.y = cvt_pk_bf16(out[2], out[3]);
        ob.z = cvt_pk_bf16(out[4], out[5]);
        ob.w = cvt_pk_bf16(out[6], out[7]);
        *reinterpret_cast<uint4*>((u16*)H + row * E_ + lane * 8) = ob;
    }
}

// ---------------------------------------------------------------- launch
extern "C" void kernel_launch(void* const* d_in, const int* in_sizes, int n_in,
                              void* d_out, int out_size, void* d_ws, size_t ws_size,
                              hipStream_t stream) {
    const float* x = (const float*)d_in[0];
    const float* WQ = (const float*)d_in[1];
    const float* bQ = (const float*)d_in[2];
    const float* WK = (const float*)d_in[3];
    const float* bK = (const float*)d_in[4];
    const float* WV = (const float*)d_in[5];
    const float* bV = (const float*)d_in[6];
    const float* WY = (const float*)d_in[7];
    const float* bY = (const float*)d_in[8];
    const float* ln1w = (const float*)d_in[9];
    const float* ln1b = (const float*)d_in[10];
    const float* W1 = (const float*)d_in[11];
    const float* b1 = (const float*)d_in[12];
    const float* W2 = (const float*)d_in[13];
    const float* b2 = (const float*)d_in[14];
    const float* ln2w = (const float*)d_in[15];
    const float* ln2b = (const float*)d_in[16];

    char* ws = (char*)d_ws;
    const size_t MB = 1024 * 1024;
    u16* WQKVT = (u16*)(ws);                              // 1.5 MiB
    u16* WYT = (u16*)(ws + (size_t)1536 * 1024);          // 0.5 MiB
    u16* W1T = (u16*)(ws + 2 * MB);                       // 2 MiB
    u16* W2T = (u16*)(ws + 4 * MB);                       // 2 MiB
    float* bqkv = (float*)(ws + 6 * MB);                  // 6 KiB
    // activation overlays (peak 103 MiB):
    u16* xb   = (u16*)(ws + 7 * MB);    // 7..23   (alive until LN1)
    u16* Qb   = (u16*)(ws + 23 * MB);   // 23..39
    u16* Kb   = (u16*)(ws + 39 * MB);   // 39..55
    u16* Vtg  = (u16*)(ws + 55 * MB);   // 55..71
    u16* Yb   = (u16*)(ws + 71 * MB);   // 71..87
    u16* attnb = Vtg;                   // 55..71 (Vtg dead after attn)
    u16* hb   = Qb;                     // 23..39 (Qb dead after attn)
    u16* hid  = Kb;                     // 39..103 (64 MiB)
    u16* m2b  = xb;                     // 7..23   (xb dead after LN1)

    dim3 blk(256);
    dim3 gblk(512);
    prep<<<dim3(7174), blk, 0, stream>>>(x, xb, WQ, WK, WV, WY, W1, W2,
                                         WQKVT, WYT, W1T, W2T, bQ, bK, bV, bqkv);
    gemm_bt<0, 1><<<dim3(12, 128), gblk, 0, stream>>>(xb, WQKVT, bqkv, Qb, Vtg, MTOT, 1536, 512);
    attn_fwd<<<dim3(512), dim3(512), 0, stream>>>(Qb, Kb, Vtg, Yb);
    gemm_bt<0, 0><<<dim3(4, 128), gblk, 0, stream>>>(Yb, WYT, bY, attnb, nullptr, MTOT, 512, 512);
    resid_ln<0><<<dim3(4096), blk, 0, stream>>>(xb, attnb, ln1w, ln1b, hb);
    gemm_bt<1, 0><<<dim3(16, 128), gblk, 0, stream>>>(hb, W1T, b1, hid, nullptr, MTOT, 2048, 512);
    gemm_bt<0, 0><<<dim3(4, 128), gblk, 0, stream>>>(hid, W2T, b2, m2b, nullptr, MTOT, 512, 2048);
    resid_ln<1><<<dim3(4096), blk, 0, stream>>>(hb, m2b, ln2w, ln2b, (float*)d_out);
}